// Round 7
// baseline (1344.881 us; speedup 1.0000x reference)
//
#include <hip/hip_runtime.h>

typedef unsigned short u16;
typedef __attribute__((ext_vector_type(8))) short short8;
typedef __attribute__((ext_vector_type(4))) float floatx4;

#define NN 50000
#define NE 1600000
#define BN_EPS 1e-5f

__device__ __forceinline__ float bfu(u16 u) {
    union { unsigned u32; float f; } v; v.u32 = ((unsigned)u) << 16; return v.f;
}
__device__ __forceinline__ u16 f2bf(float f) {
    union { float f; unsigned u; } v; v.f = f;
    unsigned r = v.u + 0x7FFFu + ((v.u >> 16) & 1u);
    return (u16)(r >> 16);
}
// mode m: 1 = buffers hold float32, 0 = buffers hold bf16
__device__ __forceinline__ float ldf(const void* p, int i, int m) {
    return m ? ((const float*)p)[i] : bfu(((const u16*)p)[i]);
}
#define MFMA __builtin_amdgcn_mfma_f32_16x16x32_bf16

// K_PREP: fused dtype-detect (per-block local) + weight canonicalize + PN + off zeroing.
__global__ __launch_bounds__(256) void k_prep(
    const u16* __restrict__ x16,
    const void* __restrict__ W0, const void* __restrict__ W1, const void* __restrict__ W2,
    const void* __restrict__ W3, const void* __restrict__ W4,
    const void* __restrict__ We0, const void* __restrict__ Wfe0,
    u16* __restrict__ dst, float* __restrict__ PN, int* __restrict__ off,
    int* __restrict__ mode) {
    __shared__ float smax[4];
    __shared__ int smode;
    int t = threadIdx.x;
    float mx = 0.f;
    for (int i = t; i < 4096; i += 256) mx = fmaxf(mx, fabsf(bfu(x16[i])));
#pragma unroll
    for (int o = 32; o > 0; o >>= 1) mx = fmaxf(mx, __shfl_down(mx, o));
    if ((t & 63) == 0) smax[t >> 6] = mx;
    __syncthreads();
    if (t == 0) {
        float m2 = fmaxf(fmaxf(smax[0], smax[1]), fmaxf(smax[2], smax[3]));
        smode = (m2 > 1e4f) ? 1 : 0;
    }
    __syncthreads();
    int m = smode;
    int bid = blockIdx.x;
    if (bid < 256) {
        int i = bid * 256 + t;
        const void* src; int o;
        if (i < 16384)      { src = W0; o = i; }
        else if (i < 24576) { src = W1; o = i - 16384; }
        else if (i < 40960) { src = W2; o = i - 24576; }
        else if (i < 49152) { src = W3; o = i - 40960; }
        else                { src = W4; o = i - 49152; }
        dst[i] = m ? f2bf(((const float*)src)[o]) : ((const u16*)src)[o];
    } else {
        if (t < 128) {
            int j = t;
            float p = 0.f, n = 0.f;
            for (int k = 0; k < 64; k++) {
                float w = ldf(We0, k, m);
                float wf = ldf(Wfe0, j * 128 + 64 + k, m);
                p += fmaxf(w, 0.f) * wf;
                n += fminf(w, 0.f) * wf;
            }
            PN[j] = p; PN[128 + j] = n;
        }
        if (t == 128) mode[0] = m;
    }
    int i2 = bid * 256 + t;
    if (i2 < NN) off[i2] = 0;
}

// K1: n1_l0[n][c] = relu(sum_i x[n][i]*Wn0[c][i])  [50000 x 64] bf16. 16 nodes/block.
__global__ __launch_bounds__(256) void k_enc0(const void* __restrict__ x, const void* __restrict__ Wn,
                                              u16* __restrict__ n1, const int* __restrict__ mf) {
    int m = mf[0];
    __shared__ float Wns[64 * 17];
    __shared__ float xsh[16][17];
    int t = threadIdx.x;
    int n0 = blockIdx.x * 16;
    for (int i = t; i < 1024; i += 256) Wns[(i >> 4) * 17 + (i & 15)] = ldf(Wn, i, m);
    { int nn = t >> 4, i = t & 15; xsh[nn][i] = ldf(x, (n0 + nn) * 16 + i, m); }
    __syncthreads();
    int c = t & 63;
#pragma unroll
    for (int nb = 0; nb < 4; nb++) {
        int nn = nb * 4 + (t >> 6);
        float acc = 0.f;
#pragma unroll
        for (int i = 0; i < 16; i++) acc += xsh[nn][i] * Wns[c * 17 + i];
        n1[(n0 + nn) * 64 + c] = f2bf(fmaxf(acc, 0.f));
    }
}

// SORT pass 1: histogram of dst
__global__ __launch_bounds__(256) void k_hist(const int* __restrict__ ei, int* __restrict__ off) {
    int e = blockIdx.x * 256 + threadIdx.x;
    atomicAdd(off + ei[NE + e], 1);
}

// two-level scan
__global__ __launch_bounds__(256) void k_scan1(const int* __restrict__ off, int* __restrict__ bs) {
    __shared__ int sh[4];
    int t = threadIdx.x;
    int i = blockIdx.x * 256 + t;
    int v = (i < NN) ? off[i] : 0;
#pragma unroll
    for (int o = 32; o > 0; o >>= 1) v += __shfl_down(v, o);
    if ((t & 63) == 0) sh[t >> 6] = v;
    __syncthreads();
    if (t == 0) bs[blockIdx.x] = sh[0] + sh[1] + sh[2] + sh[3];
}
__global__ __launch_bounds__(256) void k_scan2(int* __restrict__ bs) {
    __shared__ int s[256];
    int t = threadIdx.x;
    int v = (t < 196) ? bs[t] : 0;
    s[t] = v;
    __syncthreads();
    for (int o = 1; o < 256; o <<= 1) {
        int u = (t >= o) ? s[t - o] : 0;
        __syncthreads();
        s[t] += u;
        __syncthreads();
    }
    if (t < 196) bs[t] = s[t] - v;
}
__global__ __launch_bounds__(256) void k_scan3(int* __restrict__ off, const int* __restrict__ bs) {
    __shared__ int s[256];
    int t = threadIdx.x;
    int i = blockIdx.x * 256 + t;
    int v = (i < NN) ? off[i] : 0;
    s[t] = v;
    __syncthreads();
    for (int o = 1; o < 256; o <<= 1) {
        int u = (t >= o) ? s[t - o] : 0;
        __syncthreads();
        s[t] += u;
        __syncthreads();
    }
    if (i < NN) off[i] = bs[blockIdx.x] + s[t] - v;
}

// SORT pass 3: scatter into dst-sorted order. sd = src | dst<<16, ae bf16.
__global__ __launch_bounds__(256) void k_scatter(const int* __restrict__ ei, const void* __restrict__ ea,
                                                 int* __restrict__ off,
                                                 unsigned* __restrict__ ssd, u16* __restrict__ sae,
                                                 const int* __restrict__ mf) {
    int m = mf[0];
    int e = blockIdx.x * 256 + threadIdx.x;
    int srcv = ei[e], d = ei[NE + e];
    int p = atomicAdd(off + d, 1);
    ssd[p] = (unsigned)srcv | ((unsigned)d << 16);
    sae[p] = f2bf(ldf(ea, e, m));
}

// K5: fused edge pipeline, dst-sorted, per-wave, register-level segmented reduce.
// Wave w owns 32 edges (2 subtiles of 16). GEMM2's C-layout puts 4 consecutive
// edges in each lane's acc regs -> run detection via 4 independent shuffles,
// straight-line sum + boundary atomics. No h2 LDS, no serial chains.
__global__ __launch_bounds__(256, 8) void k_edge(
    const unsigned* __restrict__ ssd, const u16* __restrict__ sae,
    const u16* __restrict__ n1l0,
    const u16* __restrict__ Wfe0c, const void* __restrict__ bfe0,
    const float* __restrict__ PN,
    const u16* __restrict__ We1c,
    float* __restrict__ agg, float* __restrict__ sp, float* __restrict__ sn,
    const int* __restrict__ mf) {
    int m = mf[0];
    __shared__ __align__(16) u16 h1s[4][16][136];   // per-wave regions, 17408 B
    int t = threadIdx.x;
    int lane = t & 63, w = t >> 6, q = lane >> 4, nidx = lane & 15;
    int ew = blockIdx.x * 128 + w * 32;
    u16 (*h1w)[136] = h1s[w];

    // upfront: edge meta + all 8 A-fragment gathers in flight
    unsigned p0 = ssd[ew + nidx];
    unsigned p1 = ssd[ew + 16 + nidx];
    float ae0 = bfu(sae[ew + nidx]);
    float ae1 = bfu(sae[ew + 16 + nidx]);
    const u16* sr0 = n1l0 + (p0 & 0xFFFFu) * 64;
    const u16* dr0 = n1l0 + (p0 >> 16) * 64;
    const u16* sr1 = n1l0 + (p1 & 0xFFFFu) * 64;
    const u16* dr1 = n1l0 + (p1 >> 16) * 64;
    short8 as0[2], as1[2], ad0[2], ad1[2];
    as0[0] = *(const short8*)&sr0[q * 8];      as1[0] = *(const short8*)&sr0[32 + q * 8];
    ad0[0] = *(const short8*)&dr0[q * 8];      ad1[0] = *(const short8*)&dr0[32 + q * 8];
    as0[1] = *(const short8*)&sr1[q * 8];      as1[1] = *(const short8*)&sr1[32 + q * 8];
    ad0[1] = *(const short8*)&dr1[q * 8];      ad1[1] = *(const short8*)&dr1[32 + q * 8];

#pragma unroll
    for (int sub = 0; sub < 2; sub++) {
        unsigned pm = sub ? p1 : p0;
        float am = sub ? ae1 : ae0;
        float a4[4];
        int d4[4];
#pragma unroll
        for (int r = 0; r < 4; r++) {
            unsigned pe = __shfl(pm, q * 4 + r);   // edge (q*4+r) meta — independent shuffles
            d4[r] = (int)(pe >> 16);
            a4[r] = __shfl(am, q * 4 + r);
        }
        // GEMM1: h1 = relu((n1[src]+n1[dst]) @ Wfe0[:,:64]^T + ae*PN + bfe0)
#pragma unroll
        for (int jt = 0; jt < 8; jt++) {
            int j = jt * 16 + nidx;
            const u16* wr = Wfe0c + j * 128;
            short8 b0 = *(const short8*)&wr[q * 8];
            short8 b1 = *(const short8*)&wr[32 + q * 8];
            floatx4 acc = {0.f, 0.f, 0.f, 0.f};
            acc = MFMA(as0[sub], b0, acc, 0, 0, 0);
            acc = MFMA(ad0[sub], b0, acc, 0, 0, 0);
            acc = MFMA(as1[sub], b1, acc, 0, 0, 0);
            acc = MFMA(ad1[sub], b1, acc, 0, 0, 0);
            float bias = ldf(bfe0, j, m);
            float Pj = PN[j], Nj = PN[128 + j];
#pragma unroll
            for (int r = 0; r < 4; r++) {
                float a = a4[r];
                float v = acc[r] + bias + a * (a > 0.f ? Pj : Nj);
                h1w[q * 4 + r][j] = f2bf(fmaxf(v, 0.f));   // C: row=q*4+r, col=nidx+16jt
            }
        }
        asm volatile("s_waitcnt lgkmcnt(0)" ::: "memory");   // own-wave h1 writes visible
        // GEMM2 + register segmented reduce: lane holds rows q*4..q*4+3, col c
        {
            const u16* ar = &h1w[nidx][0];
            short8 a0 = *(const short8*)&ar[q * 8];
            short8 a1 = *(const short8*)&ar[32 + q * 8];
            short8 a2 = *(const short8*)&ar[64 + q * 8];
            short8 a3 = *(const short8*)&ar[96 + q * 8];
#pragma unroll
            for (int ct = 0; ct < 4; ct++) {
                int c = ct * 16 + nidx;
                const u16* wr = We1c + c * 128;
                floatx4 acc = {0.f, 0.f, 0.f, 0.f};
                acc = MFMA(a0, *(const short8*)&wr[q * 8], acc, 0, 0, 0);
                acc = MFMA(a1, *(const short8*)&wr[32 + q * 8], acc, 0, 0, 0);
                acc = MFMA(a2, *(const short8*)&wr[64 + q * 8], acc, 0, 0, 0);
                acc = MFMA(a3, *(const short8*)&wr[96 + q * 8], acc, 0, 0, 0);
                float s = fmaxf(acc[0], 0.f);
#pragma unroll
                for (int r = 1; r < 4; r++) {
                    float v = fmaxf(acc[r], 0.f);
                    if (d4[r] == d4[r - 1]) s += v;
                    else { atomicAdd(agg + d4[r - 1] * 64 + c, s); s = v; }
                }
                atomicAdd(agg + d4[3] * 64 + c, s);
            }
        }
        // sp/sn: per-dst +/- ae sums, same window reduce, 4 lanes (nidx==0)
        if (nidx == 0) {
            float ps = fmaxf(a4[0], 0.f), ns = fminf(a4[0], 0.f);
#pragma unroll
            for (int r = 1; r < 4; r++) {
                if (d4[r] == d4[r - 1]) { ps += fmaxf(a4[r], 0.f); ns += fminf(a4[r], 0.f); }
                else {
                    if (ps != 0.f) atomicAdd(sp + d4[r - 1], ps);
                    if (ns != 0.f) atomicAdd(sn + d4[r - 1], ns);
                    ps = fmaxf(a4[r], 0.f); ns = fminf(a4[r], 0.f);
                }
            }
            if (ps != 0.f) atomicAdd(sp + d4[3], ps);
            if (ns != 0.f) atomicAdd(sn + d4[3], ns);
        }
    }
}

// K_NODE: merged node MLP l0 + BN + encoder l1 + node MLP l1 + BN -> d_out. 64 nodes/block.
__global__ __launch_bounds__(256) void k_node(
    const u16* __restrict__ n1l0, const float* __restrict__ sp, const float* __restrict__ sn,
    const float* __restrict__ agg,
    const void* __restrict__ We0, const u16* __restrict__ Wfn0c, const void* __restrict__ bfn0,
    const void* __restrict__ g0, const void* __restrict__ b0,
    const void* __restrict__ rm0, const void* __restrict__ rv0,
    const u16* __restrict__ Wn1c,
    const u16* __restrict__ Wfn1c, const void* __restrict__ bfn1,
    const void* __restrict__ g1, const void* __restrict__ b1,
    const void* __restrict__ rm1, const void* __restrict__ rv1,
    void* __restrict__ out, const int* __restrict__ mf) {
    int m = mf[0];
    __shared__ __align__(16) u16 fs[64][136];
    __shared__ __align__(16) u16 xs[64][136];
    int t = threadIdx.x;
    int n0 = blockIdx.x * 64;
    {   // fs = concat(analytic agg_l0, n1_l0)
        int col = t & 127, rbase = t >> 7;
        float wp = 0.f, wn = 0.f;
        if (col < 64) { float w0 = ldf(We0, col, m); wp = fmaxf(w0, 0.f); wn = fminf(w0, 0.f); }
#pragma unroll
        for (int i = 0; i < 32; i++) {
            int row = rbase + 2 * i;
            int n = n0 + row;
            float v = 0.f;
            if (n < NN) v = (col < 64) ? (wp * sp[n] + wn * sn[n]) : bfu(n1l0[n * 64 + col - 64]);
            fs[row][col] = f2bf(v);
        }
    }
    __syncthreads();
    int lane = t & 63, w = t >> 6, q = lane >> 4, nidx = lane & 15;
    {   // GEMM1: x1 = BN(relu(fs @ Wfn0^T + bfn0)) -> xs (own rows)
        const u16* ar = &fs[w * 16 + nidx][0];
        short8 a0 = *(const short8*)&ar[q * 8];
        short8 a1 = *(const short8*)&ar[32 + q * 8];
        short8 a2 = *(const short8*)&ar[64 + q * 8];
        short8 a3 = *(const short8*)&ar[96 + q * 8];
#pragma unroll
        for (int jt = 0; jt < 8; jt++) {
            int j = jt * 16 + nidx;
            const u16* wr = Wfn0c + j * 128;
            floatx4 acc = {0.f, 0.f, 0.f, 0.f};
            acc = MFMA(a0, *(const short8*)&wr[q * 8], acc, 0, 0, 0);
            acc = MFMA(a1, *(const short8*)&wr[32 + q * 8], acc, 0, 0, 0);
            acc = MFMA(a2, *(const short8*)&wr[64 + q * 8], acc, 0, 0, 0);
            acc = MFMA(a3, *(const short8*)&wr[96 + q * 8], acc, 0, 0, 0);
            float bias = ldf(bfn0, j, m);
            float sc = ldf(g0, j, m) * rsqrtf(ldf(rv0, j, m) + BN_EPS);
            float sh = ldf(b0, j, m) - ldf(rm0, j, m) * sc;
#pragma unroll
            for (int r = 0; r < 4; r++)
                xs[w * 16 + q * 4 + r][j] = f2bf(fmaxf(acc[r] + bias, 0.f) * sc + sh);
        }
    }
    asm volatile("s_waitcnt lgkmcnt(0)" ::: "memory");   // own-wave xs writes
    {   // GEMM2: n1_l1 = relu(xs @ Wn1^T) -> fs[row][64+j] (own rows)
        const u16* ar = &xs[w * 16 + nidx][0];
        short8 a0 = *(const short8*)&ar[q * 8];
        short8 a1 = *(const short8*)&ar[32 + q * 8];
        short8 a2 = *(const short8*)&ar[64 + q * 8];
        short8 a3 = *(const short8*)&ar[96 + q * 8];
#pragma unroll
        for (int jt = 0; jt < 4; jt++) {
            int j = jt * 16 + nidx;
            const u16* wr = Wn1c + j * 128;
            floatx4 acc = {0.f, 0.f, 0.f, 0.f};
            acc = MFMA(a0, *(const short8*)&wr[q * 8], acc, 0, 0, 0);
            acc = MFMA(a1, *(const short8*)&wr[32 + q * 8], acc, 0, 0, 0);
            acc = MFMA(a2, *(const short8*)&wr[64 + q * 8], acc, 0, 0, 0);
            acc = MFMA(a3, *(const short8*)&wr[96 + q * 8], acc, 0, 0, 0);
#pragma unroll
            for (int r = 0; r < 4; r++)
                fs[w * 16 + q * 4 + r][64 + j] = f2bf(fmaxf(acc[r], 0.f));
        }
    }
    __syncthreads();
    {   // stage agg into fs[][0..63]
#pragma unroll
        for (int i = 0; i < 16; i++) {
            int idx = i * 256 + t;
            int row = idx >> 6, c = idx & 63;
            int n = n0 + row;
            fs[row][c] = f2bf((n < NN) ? agg[n * 64 + c] : 0.f);
        }
    }
    __syncthreads();
    {   // GEMM3: out = BN(relu(fs @ Wfn1^T + bfn1))
        const u16* ar = &fs[w * 16 + nidx][0];
        short8 a0 = *(const short8*)&ar[q * 8];
        short8 a1 = *(const short8*)&ar[32 + q * 8];
        short8 a2 = *(const short8*)&ar[64 + q * 8];
        short8 a3 = *(const short8*)&ar[96 + q * 8];
#pragma unroll
        for (int jt = 0; jt < 8; jt++) {
            int j = jt * 16 + nidx;
            const u16* wr = Wfn1c + j * 128;
            floatx4 acc = {0.f, 0.f, 0.f, 0.f};
            acc = MFMA(a0, *(const short8*)&wr[q * 8], acc, 0, 0, 0);
            acc = MFMA(a1, *(const short8*)&wr[32 + q * 8], acc, 0, 0, 0);
            acc = MFMA(a2, *(const short8*)&wr[64 + q * 8], acc, 0, 0, 0);
            acc = MFMA(a3, *(const short8*)&wr[96 + q * 8], acc, 0, 0, 0);
            float bias = ldf(bfn1, j, m);
            float sc = ldf(g1, j, m) * rsqrtf(ldf(rv1, j, m) + BN_EPS);
            float sh = ldf(b1, j, m) - ldf(rm1, j, m) * sc;
#pragma unroll
            for (int r = 0; r < 4; r++) {
                int n = n0 + w * 16 + q * 4 + r;
                if (n < NN) {
                    float v = fmaxf(acc[r] + bias, 0.f) * sc + sh;
                    if (m) ((float*)out)[n * 128 + j] = v;
                    else   ((u16*)out)[n * 128 + j] = f2bf(v);
                }
            }
        }
    }
}

extern "C" void kernel_launch(void* const* d_in, const int* in_sizes, int n_in,
                              void* d_out, int out_size, void* d_ws, size_t ws_size,
                              hipStream_t stream) {
    const void* x    = d_in[0];
    const void* ea   = d_in[1];
    const int*  ei   = (const int*)d_in[2];
    const void* Wn0  = d_in[3];
    const void* We0  = d_in[4];
    const void* Wfn0 = d_in[5];
    const void* bfn0 = d_in[6];
    const void* Wfe0 = d_in[7];
    const void* bfe0 = d_in[8];
    const void* g0   = d_in[9];
    const void* b0   = d_in[10];
    const void* rm0  = d_in[11];
    const void* rv0  = d_in[12];
    const void* Wn1  = d_in[13];
    const void* We1  = d_in[14];
    const void* Wfn1 = d_in[15];
    const void* bfn1 = d_in[16];
    // d_in[17]/d_in[18] (l1_Wfe/l1_bfe): dead — layer-1 edge output discarded
    const void* g1   = d_in[19];
    const void* b1   = d_in[20];
    const void* rm1  = d_in[21];
    const void* rv1  = d_in[22];

    float* wsf = (float*)d_ws;
    float*    agg  = wsf;                         // 3.2M f32
    float*    sp   = wsf + 3200000;               // 50K
    float*    sn   = wsf + 3250000;               // 50K
    u16*      n1l0 = (u16*)(wsf + 3300000);       // 3.2M u16 (1.6M slots)
    unsigned* ssd  = (unsigned*)(wsf + 4900000);  // 1.6M uint
    u16*      sae  = (u16*)(wsf + 6500000);       // 1.6M u16 (0.8M slots)
    float*    PN   = wsf + 7300000;               // 256
    u16*      Wc   = (u16*)(wsf + 7300256);       // 65,536 u16 (32,768 slots)
    int*      off  = (int*)(wsf + 7333024);       // 50,000 int
    int*      bs   = (int*)(wsf + 7383024);       // 256 int
    int*      mode = (int*)(wsf + 7383280);
    u16* Wfe0c = Wc;
    u16* We1c  = Wc + 16384;
    u16* Wfn0c = Wc + 24576;
    u16* Wn1c  = Wc + 40960;
    u16* Wfn1c = Wc + 49152;

    hipMemsetAsync(agg, 0, 3300000 * sizeof(float), stream);   // agg + sp + sn

    k_prep<<<257, 256, 0, stream>>>((const u16*)x, Wfe0, We1, Wfn0, Wn1, Wfn1,
                                    We0, Wfe0, Wc, PN, off, mode);
    k_enc0<<<3125, 256, 0, stream>>>(x, Wn0, n1l0, mode);
    k_hist<<<6250, 256, 0, stream>>>(ei, off);
    k_scan1<<<196, 256, 0, stream>>>(off, bs);
    k_scan2<<<1, 256, 0, stream>>>(bs);
    k_scan3<<<196, 256, 0, stream>>>(off, bs);
    k_scatter<<<6250, 256, 0, stream>>>(ei, ea, off, ssd, sae, mode);
    k_edge<<<12500, 256, 0, stream>>>(ssd, sae, n1l0, Wfe0c, bfe0, PN, We1c,
                                      agg, sp, sn, mode);
    k_node<<<782, 256, 0, stream>>>(n1l0, sp, sn, agg, We0, Wfn0c, bfn0,
                                    g0, b0, rm0, rv0, Wn1c, Wfn1c, bfn1,
                                    g1, b1, rm1, rv1, d_out, mode);
}

// Round 8
// 980.849 us; speedup vs baseline: 1.3711x; 1.3711x over previous
//
#include <hip/hip_runtime.h>

typedef unsigned short u16;
typedef __attribute__((ext_vector_type(8))) short short8;
typedef __attribute__((ext_vector_type(4))) float floatx4;

#define NN 50000
#define NE 1600000
#define BN_EPS 1e-5f

__device__ __forceinline__ float bfu(u16 u) {
    union { unsigned u32; float f; } v; v.u32 = ((unsigned)u) << 16; return v.f;
}
__device__ __forceinline__ u16 f2bf(float f) {
    union { float f; unsigned u; } v; v.f = f;
    unsigned r = v.u + 0x7FFFu + ((v.u >> 16) & 1u);
    return (u16)(r >> 16);
}
// mode m: 1 = buffers hold float32, 0 = buffers hold bf16
__device__ __forceinline__ float ldf(const void* p, int i, int m) {
    return m ? ((const float*)p)[i] : bfu(((const u16*)p)[i]);
}
#define MFMA __builtin_amdgcn_mfma_f32_16x16x32_bf16

// K_PREP: dtype-detect (per-block) + weight canonicalize (bf16) + PN + off zeroing.
// Wc layout (u16): Wfe0[16384] | We1[8192] | Wfn0[16384] | Wn1[8192] | Wfn1[16384] | Wn0[1024]
__global__ __launch_bounds__(256) void k_prep(
    const u16* __restrict__ x16,
    const void* __restrict__ W0, const void* __restrict__ W1, const void* __restrict__ W2,
    const void* __restrict__ W3, const void* __restrict__ W4, const void* __restrict__ W5,
    const void* __restrict__ We0, const void* __restrict__ Wfe0,
    u16* __restrict__ dst, float* __restrict__ PN, int* __restrict__ off,
    int* __restrict__ mode) {
    __shared__ float smax[4];
    __shared__ int smode;
    int t = threadIdx.x;
    float mx = 0.f;
    for (int i = t; i < 4096; i += 256) mx = fmaxf(mx, fabsf(bfu(x16[i])));
#pragma unroll
    for (int o = 32; o > 0; o >>= 1) mx = fmaxf(mx, __shfl_down(mx, o));
    if ((t & 63) == 0) smax[t >> 6] = mx;
    __syncthreads();
    if (t == 0) {
        float m2 = fmaxf(fmaxf(smax[0], smax[1]), fmaxf(smax[2], smax[3]));
        smode = (m2 > 1e4f) ? 1 : 0;
    }
    __syncthreads();
    int m = smode;
    int bid = blockIdx.x;
    if (bid < 260) {
        int i = bid * 256 + t;   // < 66560
        const void* src; int o;
        if (i < 16384)      { src = W0; o = i; }
        else if (i < 24576) { src = W1; o = i - 16384; }
        else if (i < 40960) { src = W2; o = i - 24576; }
        else if (i < 49152) { src = W3; o = i - 40960; }
        else if (i < 65536) { src = W4; o = i - 49152; }
        else                { src = W5; o = i - 65536; }
        dst[i] = m ? f2bf(((const float*)src)[o]) : ((const u16*)src)[o];
    } else {
        if (t < 128) {
            int j = t;
            float p = 0.f, n = 0.f;
            for (int k = 0; k < 64; k++) {
                float w = ldf(We0, k, m);
                float wf = ldf(Wfe0, j * 128 + 64 + k, m);
                p += fmaxf(w, 0.f) * wf;
                n += fminf(w, 0.f) * wf;
            }
            PN[j] = p; PN[128 + j] = n;
        }
        if (t == 128) mode[0] = m;
    }
    int i2 = bid * 256 + t;
    if (i2 < NN) off[i2] = 0;
}

// K_ENC: per 64-node block: n1 = relu(x@Wn0^T) (MFMA, K=16 zero-padded to 32, LDS only),
// then z' = n1 @ Wfe0[:, :64]^T + 0.5*bfe0 -> zb bf16 [NN][128]. Barrier-free (per-wave rows).
__global__ __launch_bounds__(256) void k_enc(
    const void* __restrict__ x, const u16* __restrict__ Wn0c,
    const u16* __restrict__ Wfe0c, const void* __restrict__ bfe0,
    u16* __restrict__ zb, const int* __restrict__ mf) {
    int m = mf[0];
    __shared__ __align__(16) u16 n1ls[64][72];
    int t = threadIdx.x, lane = t & 63, w = t >> 6, q = lane >> 4, nidx = lane & 15;
    int n0 = blockIdx.x * 64;
    int arow = w * 16 + nidx;
    int an = n0 + arow;
    short8 ax = {0, 0, 0, 0, 0, 0, 0, 0};
    if (q < 2 && an < NN) {
        union { short8 v; u16 a[8]; } o;
#pragma unroll
        for (int i = 0; i < 8; i++) o.a[i] = f2bf(ldf(x, an * 16 + q * 8 + i, m));
        ax = o.v;
    }
#pragma unroll
    for (int jt = 0; jt < 4; jt++) {
        int j = jt * 16 + nidx;
        short8 bx = {0, 0, 0, 0, 0, 0, 0, 0};
        if (q < 2) bx = *(const short8*)&Wn0c[j * 16 + q * 8];
        floatx4 c4 = {0.f, 0.f, 0.f, 0.f};
        c4 = MFMA(ax, bx, c4, 0, 0, 0);
#pragma unroll
        for (int r = 0; r < 4; r++)
            n1ls[w * 16 + q * 4 + r][j] = f2bf(fmaxf(c4[r], 0.f));
    }
    asm volatile("s_waitcnt lgkmcnt(0)" ::: "memory");
    const u16* ar = &n1ls[arow][0];
    short8 a0 = *(const short8*)&ar[q * 8];
    short8 a1 = *(const short8*)&ar[32 + q * 8];
#pragma unroll
    for (int jt = 0; jt < 8; jt++) {
        int j = jt * 16 + nidx;
        const u16* wr = Wfe0c + j * 128;
        floatx4 c4 = {0.f, 0.f, 0.f, 0.f};
        c4 = MFMA(a0, *(const short8*)&wr[q * 8], c4, 0, 0, 0);
        c4 = MFMA(a1, *(const short8*)&wr[32 + q * 8], c4, 0, 0, 0);
        float bh = 0.5f * ldf(bfe0, j, m);
#pragma unroll
        for (int r = 0; r < 4; r++) {
            int n = n0 + w * 16 + q * 4 + r;
            if (n < NN) zb[n * 128 + j] = f2bf(c4[r] + bh);
        }
    }
}

// SORT pass 1: histogram of dst
__global__ __launch_bounds__(256) void k_hist(const int* __restrict__ ei, int* __restrict__ off) {
    int e = blockIdx.x * 256 + threadIdx.x;
    atomicAdd(off + ei[NE + e], 1);
}

// two-level scan
__global__ __launch_bounds__(256) void k_scan1(const int* __restrict__ off, int* __restrict__ bs) {
    __shared__ int sh[4];
    int t = threadIdx.x;
    int i = blockIdx.x * 256 + t;
    int v = (i < NN) ? off[i] : 0;
#pragma unroll
    for (int o = 32; o > 0; o >>= 1) v += __shfl_down(v, o);
    if ((t & 63) == 0) sh[t >> 6] = v;
    __syncthreads();
    if (t == 0) bs[blockIdx.x] = sh[0] + sh[1] + sh[2] + sh[3];
}
__global__ __launch_bounds__(256) void k_scan2(int* __restrict__ bs) {
    __shared__ int s[256];
    int t = threadIdx.x;
    int v = (t < 196) ? bs[t] : 0;
    s[t] = v;
    __syncthreads();
    for (int o = 1; o < 256; o <<= 1) {
        int u = (t >= o) ? s[t - o] : 0;
        __syncthreads();
        s[t] += u;
        __syncthreads();
    }
    if (t < 196) bs[t] = s[t] - v;
}
__global__ __launch_bounds__(256) void k_scan3(int* __restrict__ off, const int* __restrict__ bs) {
    __shared__ int s[256];
    int t = threadIdx.x;
    int i = blockIdx.x * 256 + t;
    int v = (i < NN) ? off[i] : 0;
    s[t] = v;
    __syncthreads();
    for (int o = 1; o < 256; o <<= 1) {
        int u = (t >= o) ? s[t - o] : 0;
        __syncthreads();
        s[t] += u;
        __syncthreads();
    }
    if (i < NN) off[i] = bs[blockIdx.x] + s[t] - v;
}

// SORT pass 3: scatter into dst-sorted order. ssrc u16, ae bf16. (dst implicit via off runs)
__global__ __launch_bounds__(256) void k_scatter(const int* __restrict__ ei, const void* __restrict__ ea,
                                                 int* __restrict__ off,
                                                 u16* __restrict__ ssrc, u16* __restrict__ sae,
                                                 const int* __restrict__ mf) {
    int m = mf[0];
    int e = blockIdx.x * 256 + threadIdx.x;
    int srcv = ei[e], d = ei[NE + e];
    int p = atomicAdd(off + d, 1);
    ssrc[p] = (u16)srcv;
    sae[p] = f2bf(ldf(ea, e, m));
}

// K_EDGE: block owns dst nodes [16b,16b+16). h1 built in registers from z gathers
// (GEMM1 hoisted into k_enc), GEMM2 via MFMA, e1' accumulated via LDS ds_add_f32.
// Epilogue: plain coalesced stores of aggb (bf16) + sp/sn. Zero global atomics.
__global__ __launch_bounds__(256) void k_edge(
    const u16* __restrict__ ssrc, const u16* __restrict__ sae,
    const u16* __restrict__ zb,
    const float* __restrict__ PN, const u16* __restrict__ We1c,
    const int* __restrict__ off,
    u16* __restrict__ aggb, float* __restrict__ sp, float* __restrict__ sn) {
    __shared__ float acc[17][68];
    __shared__ float spn[2][17];
    int t = threadIdx.x, lane = t & 63, w = t >> 6, q = lane >> 4, nidx = lane & 15;
    int nstart = blockIdx.x * 16;
    for (int i = t; i < 17 * 68; i += 256) ((float*)acc)[i] = 0.f;
    if (t < 34) ((float*)spn)[t] = 0.f;
    __syncthreads();
    int ebeg = (nstart == 0) ? 0 : off[nstart - 1];
    int eend = off[nstart + 15];
    for (int e0 = ebeg + w * 16; e0 < eend; e0 += 64) {
        int el = e0 + nidx;
        bool ok = el < eend;
        int ec = ok ? el : (eend - 1);
        int srcn = (int)ssrc[ec];
        float ae = ok ? bfu(sae[ec]) : 0.f;
        int slot = 0;
#pragma unroll
        for (int k2 = 0; k2 < 16; k2++) slot += (ec >= off[nstart + k2]) ? 1 : 0;  // scalar bounds
        if (!ok) slot = 16;
        const u16* zs = zb + srcn * 128;
        const u16* zd = zb + (nstart + (slot < 16 ? slot : 0)) * 128;
        const float* pnl = (ae > 0.f) ? PN : PN + 128;
        short8 afr[4];
#pragma unroll
        for (int ks = 0; ks < 4; ks++) {
            int cb = ks * 32 + q * 8;
            short8 vs = *(const short8*)&zs[cb];
            short8 vd = *(const short8*)&zd[cb];
            union { short8 v; u16 a[8]; } o;
#pragma unroll
            for (int i = 0; i < 8; i++) {
                float f = bfu((u16)vs[i]) + bfu((u16)vd[i]) + ae * pnl[cb + i];
                o.a[i] = f2bf(fmaxf(f, 0.f));
            }
            afr[ks] = o.v;
        }
        int s4[4];
#pragma unroll
        for (int r = 0; r < 4; r++) s4[r] = __shfl(slot, q * 4 + r);
#pragma unroll
        for (int ct = 0; ct < 4; ct++) {
            int c = ct * 16 + nidx;
            const u16* wr = We1c + c * 128;
            floatx4 a4 = {0.f, 0.f, 0.f, 0.f};
            a4 = MFMA(afr[0], *(const short8*)&wr[q * 8], a4, 0, 0, 0);
            a4 = MFMA(afr[1], *(const short8*)&wr[32 + q * 8], a4, 0, 0, 0);
            a4 = MFMA(afr[2], *(const short8*)&wr[64 + q * 8], a4, 0, 0, 0);
            a4 = MFMA(afr[3], *(const short8*)&wr[96 + q * 8], a4, 0, 0, 0);
#pragma unroll
            for (int r = 0; r < 4; r++)
                atomicAdd(&acc[s4[r]][c], fmaxf(a4[r], 0.f));   // ds_add_f32, LDS only
        }
        if (q == 0 && ok) {
            atomicAdd(&spn[0][slot], fmaxf(ae, 0.f));
            atomicAdd(&spn[1][slot], fminf(ae, 0.f));
        }
    }
    __syncthreads();
    for (int i = t; i < 1024; i += 256) {
        int row = i >> 6, c = i & 63;
        aggb[(nstart + row) * 64 + c] = f2bf(acc[row][c]);
    }
    if (t < 16) { sp[nstart + t] = spn[0][t]; sn[nstart + t] = spn[1][t]; }
}

// K_NODE: barrier-free per-wave. Recomputes n1 (MFMA), analytic agg_l0, MLP l0 + BN,
// encoder l1, stage aggb, MLP l1 + BN -> out. 64 nodes/block.
__global__ __launch_bounds__(256) void k_node(
    const void* __restrict__ x, const float* __restrict__ sp, const float* __restrict__ sn,
    const u16* __restrict__ aggb,
    const void* __restrict__ We0, const u16* __restrict__ Wn0c,
    const u16* __restrict__ Wfn0c, const void* __restrict__ bfn0,
    const void* __restrict__ g0, const void* __restrict__ b0,
    const void* __restrict__ rm0, const void* __restrict__ rv0,
    const u16* __restrict__ Wn1c,
    const u16* __restrict__ Wfn1c, const void* __restrict__ bfn1,
    const void* __restrict__ g1, const void* __restrict__ b1,
    const void* __restrict__ rm1, const void* __restrict__ rv1,
    void* __restrict__ out, const int* __restrict__ mf) {
    int m = mf[0];
    __shared__ __align__(16) u16 fs[64][136];
    __shared__ __align__(16) u16 xs[64][136];
    int t = threadIdx.x, lane = t & 63, w = t >> 6, q = lane >> 4, nidx = lane & 15;
    int n0 = blockIdx.x * 64;
    int arow = w * 16 + nidx;
    int an = n0 + arow;
    // n1 recompute -> fs[own rows][64+j]
    {
        short8 ax = {0, 0, 0, 0, 0, 0, 0, 0};
        if (q < 2 && an < NN) {
            union { short8 v; u16 a[8]; } o;
#pragma unroll
            for (int i = 0; i < 8; i++) o.a[i] = f2bf(ldf(x, an * 16 + q * 8 + i, m));
            ax = o.v;
        }
#pragma unroll
        for (int jt = 0; jt < 4; jt++) {
            int j = jt * 16 + nidx;
            short8 bx = {0, 0, 0, 0, 0, 0, 0, 0};
            if (q < 2) bx = *(const short8*)&Wn0c[j * 16 + q * 8];
            floatx4 c4 = {0.f, 0.f, 0.f, 0.f};
            c4 = MFMA(ax, bx, c4, 0, 0, 0);
#pragma unroll
            for (int r = 0; r < 4; r++)
                fs[w * 16 + q * 4 + r][64 + j] = f2bf(fmaxf(c4[r], 0.f));
        }
    }
    // fs[own rows][0..63] = analytic agg_l0 (rank-1 from sp/sn)
    {
        float w0 = ldf(We0, lane, m);
        float wp = fmaxf(w0, 0.f), wn = fminf(w0, 0.f);
#pragma unroll
        for (int st = 0; st < 16; st++) {
            int row = w * 16 + st;
            int n = n0 + row;
            float v = (n < NN) ? (wp * sp[n] + wn * sn[n]) : 0.f;
            fs[row][lane] = f2bf(v);
        }
    }
    asm volatile("s_waitcnt lgkmcnt(0)" ::: "memory");
    // GEMM1: x1 = BN(relu(fs @ Wfn0^T + bfn0)) -> xs (own rows)
    {
        const u16* ar = &fs[arow][0];
        short8 a0 = *(const short8*)&ar[q * 8];
        short8 a1 = *(const short8*)&ar[32 + q * 8];
        short8 a2 = *(const short8*)&ar[64 + q * 8];
        short8 a3 = *(const short8*)&ar[96 + q * 8];
#pragma unroll
        for (int jt = 0; jt < 8; jt++) {
            int j = jt * 16 + nidx;
            const u16* wr = Wfn0c + j * 128;
            floatx4 c4 = {0.f, 0.f, 0.f, 0.f};
            c4 = MFMA(a0, *(const short8*)&wr[q * 8], c4, 0, 0, 0);
            c4 = MFMA(a1, *(const short8*)&wr[32 + q * 8], c4, 0, 0, 0);
            c4 = MFMA(a2, *(const short8*)&wr[64 + q * 8], c4, 0, 0, 0);
            c4 = MFMA(a3, *(const short8*)&wr[96 + q * 8], c4, 0, 0, 0);
            float bias = ldf(bfn0, j, m);
            float sc = ldf(g0, j, m) * rsqrtf(ldf(rv0, j, m) + BN_EPS);
            float sh = ldf(b0, j, m) - ldf(rm0, j, m) * sc;
#pragma unroll
            for (int r = 0; r < 4; r++)
                xs[w * 16 + q * 4 + r][j] = f2bf(fmaxf(c4[r] + bias, 0.f) * sc + sh);
        }
    }
    asm volatile("s_waitcnt lgkmcnt(0)" ::: "memory");
    // GEMM2: n1_l1 = relu(xs @ Wn1^T) -> fs[own rows][64+j] (overwrite dead n1_l0)
    {
        const u16* ar = &xs[arow][0];
        short8 a0 = *(const short8*)&ar[q * 8];
        short8 a1 = *(const short8*)&ar[32 + q * 8];
        short8 a2 = *(const short8*)&ar[64 + q * 8];
        short8 a3 = *(const short8*)&ar[96 + q * 8];
#pragma unroll
        for (int jt = 0; jt < 4; jt++) {
            int j = jt * 16 + nidx;
            const u16* wr = Wn1c + j * 128;
            floatx4 c4 = {0.f, 0.f, 0.f, 0.f};
            c4 = MFMA(a0, *(const short8*)&wr[q * 8], c4, 0, 0, 0);
            c4 = MFMA(a1, *(const short8*)&wr[32 + q * 8], c4, 0, 0, 0);
            c4 = MFMA(a2, *(const short8*)&wr[64 + q * 8], c4, 0, 0, 0);
            c4 = MFMA(a3, *(const short8*)&wr[96 + q * 8], c4, 0, 0, 0);
#pragma unroll
            for (int r = 0; r < 4; r++)
                fs[w * 16 + q * 4 + r][64 + j] = f2bf(fmaxf(c4[r], 0.f));
        }
    }
    // stage aggb (bf16 direct copy) -> fs[own rows][0..63]
#pragma unroll
    for (int st = 0; st < 16; st++) {
        int row = w * 16 + st;
        int n = n0 + row;
        fs[row][lane] = (n < NN) ? aggb[n * 64 + lane] : (u16)0;
    }
    asm volatile("s_waitcnt lgkmcnt(0)" ::: "memory");
    // GEMM3: out = BN(relu(fs @ Wfn1^T + bfn1))
    {
        const u16* ar = &fs[arow][0];
        short8 a0 = *(const short8*)&ar[q * 8];
        short8 a1 = *(const short8*)&ar[32 + q * 8];
        short8 a2 = *(const short8*)&ar[64 + q * 8];
        short8 a3 = *(const short8*)&ar[96 + q * 8];
#pragma unroll
        for (int jt = 0; jt < 8; jt++) {
            int j = jt * 16 + nidx;
            const u16* wr = Wfn1c + j * 128;
            floatx4 c4 = {0.f, 0.f, 0.f, 0.f};
            c4 = MFMA(a0, *(const short8*)&wr[q * 8], c4, 0, 0, 0);
            c4 = MFMA(a1, *(const short8*)&wr[32 + q * 8], c4, 0, 0, 0);
            c4 = MFMA(a2, *(const short8*)&wr[64 + q * 8], c4, 0, 0, 0);
            c4 = MFMA(a3, *(const short8*)&wr[96 + q * 8], c4, 0, 0, 0);
            float bias = ldf(bfn1, j, m);
            float sc = ldf(g1, j, m) * rsqrtf(ldf(rv1, j, m) + BN_EPS);
            float sh = ldf(b1, j, m) - ldf(rm1, j, m) * sc;
#pragma unroll
            for (int r = 0; r < 4; r++) {
                int n = n0 + w * 16 + q * 4 + r;
                if (n < NN) {
                    float v = fmaxf(c4[r] + bias, 0.f) * sc + sh;
                    if (m) ((float*)out)[n * 128 + j] = v;
                    else   ((u16*)out)[n * 128 + j] = f2bf(v);
                }
            }
        }
    }
}

extern "C" void kernel_launch(void* const* d_in, const int* in_sizes, int n_in,
                              void* d_out, int out_size, void* d_ws, size_t ws_size,
                              hipStream_t stream) {
    const void* x    = d_in[0];
    const void* ea   = d_in[1];
    const int*  ei   = (const int*)d_in[2];
    const void* Wn0  = d_in[3];
    const void* We0  = d_in[4];
    const void* Wfn0 = d_in[5];
    const void* bfn0 = d_in[6];
    const void* Wfe0 = d_in[7];
    const void* bfe0 = d_in[8];
    const void* g0   = d_in[9];
    const void* b0   = d_in[10];
    const void* rm0  = d_in[11];
    const void* rv0  = d_in[12];
    const void* Wn1  = d_in[13];
    const void* We1  = d_in[14];
    const void* Wfn1 = d_in[15];
    const void* bfn1 = d_in[16];
    // d_in[17]/d_in[18] (l1_Wfe/l1_bfe): dead — layer-1 edge output discarded
    const void* g1   = d_in[19];
    const void* b1   = d_in[20];
    const void* rm1  = d_in[21];
    const void* rv1  = d_in[22];

    float* wsf = (float*)d_ws;
    u16*   aggb = (u16*)wsf;                      // 3.2M u16 = 1.6M slots
    float* sp   = wsf + 1600000;                  // 50K
    float* sn   = wsf + 1650000;                  // 50K
    u16*   zb   = (u16*)(wsf + 1700000);          // 6.4M u16 = 3.2M slots
    u16*   ssrc = (u16*)(wsf + 4900000);          // 1.6M u16 = 0.8M slots
    u16*   sae  = (u16*)(wsf + 5700000);          // 1.6M u16 = 0.8M slots
    float* PN   = wsf + 6500000;                  // 256
    u16*   Wc   = (u16*)(wsf + 6500256);          // 66,560 u16 = 33,280 slots
    int*   off  = (int*)(wsf + 6533536);          // 50,000
    int*   bs   = (int*)(wsf + 6583536);          // 256
    int*   mode = (int*)(wsf + 6583792);          // 1   (total 26.3 MB)
    u16* Wfe0c = Wc;
    u16* We1c  = Wc + 16384;
    u16* Wfn0c = Wc + 24576;
    u16* Wn1c  = Wc + 40960;
    u16* Wfn1c = Wc + 49152;
    u16* Wn0c  = Wc + 65536;

    k_prep<<<261, 256, 0, stream>>>((const u16*)x, Wfe0, We1, Wfn0, Wn1, Wfn1, Wn0,
                                    We0, Wfe0, Wc, PN, off, mode);
    k_enc<<<782, 256, 0, stream>>>(x, Wn0c, Wfe0c, bfe0, zb, mode);
    k_hist<<<6250, 256, 0, stream>>>(ei, off);
    k_scan1<<<196, 256, 0, stream>>>(off, bs);
    k_scan2<<<1, 256, 0, stream>>>(bs);
    k_scan3<<<196, 256, 0, stream>>>(off, bs);
    k_scatter<<<6250, 256, 0, stream>>>(ei, ea, off, ssrc, sae, mode);
    k_edge<<<3125, 256, 0, stream>>>(ssrc, sae, zb, PN, We1c, off, aggb, sp, sn);
    k_node<<<782, 256, 0, stream>>>(x, sp, sn, aggb, We0, Wn0c, Wfn0c, bfn0,
                                    g0, b0, rm0, rv0, Wn1c, Wfn1c, bfn1,
                                    g1, b1, rm1, rv1, d_out, mode);
}